// Round 1
// baseline (168.199 us; speedup 1.0000x reference)
//
#include <hip/hip_runtime.h>
#include <hip/hip_bf16.h>
#include <math.h>

typedef __bf16 bf16_t;
typedef __bf16 bf16x8 __attribute__((ext_vector_type(8)));
typedef float  f32x4  __attribute__((ext_vector_type(4)));

static constexpr int Bz = 8, Tt = 2048, Cc = 1024, Dd = 128;
static constexpr int Mm = Bz * Tt;   // 16384

__device__ __forceinline__ bf16x8 lds_read8(const bf16_t* base, int byte) {
    return *(const bf16x8*)((const char*)base + byte);
}

__device__ __forceinline__ bf16x8 cvt8(float4 a, float4 b) {
    bf16x8 r;
    r[0] = (bf16_t)a.x; r[1] = (bf16_t)a.y; r[2] = (bf16_t)a.z; r[3] = (bf16_t)a.w;
    r[4] = (bf16_t)b.x; r[5] = (bf16_t)b.y; r[6] = (bf16_t)b.z; r[7] = (bf16_t)b.w;
    return r;
}

// ---------------- QKV projection GEMM ----------------
// grid (Mm/128, 3), block 256. y==0 -> q [M][D], y==1 -> k [M][D], y==2 -> vT [D][M]
__global__ __launch_bounds__(256) void qkv_kernel(
    const float* __restrict__ x,
    const float* __restrict__ Wq, const float* __restrict__ bq,
    const float* __restrict__ Wk, const float* __restrict__ bk,
    const float* __restrict__ Wv, const float* __restrict__ bv,
    bf16_t* __restrict__ qo, bf16_t* __restrict__ ko, bf16_t* __restrict__ vTo)
{
    const int y = blockIdx.y;
    const float* W    = (y == 0) ? Wq : (y == 1) ? Wk : Wv;
    const float* bias = (y == 0) ? bq : (y == 1) ? bk : bv;

    const int m0   = blockIdx.x * 128;
    const int tid  = threadIdx.x;
    const int lane = tid & 63;
    const int w    = tid >> 6;
    const int wr   = w >> 1;          // wave row (0..1) * 64
    const int wc   = w & 1;           // wave col (0..1) * 64
    const int lo   = lane & 15;
    const int hi   = lane >> 4;

    __shared__ bf16_t Xs[128 * 64];   // [m][c] bf16, rows 128B, XOR-swizzled
    __shared__ bf16_t Ws_[128 * 64];  // [d][c] bf16, same layout

    f32x4 zero4 = {0.f, 0.f, 0.f, 0.f};
    f32x4 acc[4][4];
    #pragma unroll
    for (int i = 0; i < 4; i++)
        #pragma unroll
        for (int j = 0; j < 4; j++) acc[i][j] = zero4;

    const int srow = tid >> 1;          // 0..127
    const int scol = (tid & 1) * 32;    // 0 or 32

    for (int k0 = 0; k0 < Cc; k0 += 64) {
        __syncthreads();
        {
            const float4* sx = (const float4*)(x + (size_t)(m0 + srow) * Cc + k0 + scol);
            const float4* sw = (const float4*)(W + (size_t)srow * Cc + k0 + scol);
            float4 fx[8], fw[8];
            #pragma unroll
            for (int i = 0; i < 8; i++) fx[i] = sx[i];
            #pragma unroll
            for (int i = 0; i < 8; i++) fw[i] = sw[i];
            #pragma unroll
            for (int j = 0; j < 4; j++) {
                int byte = (srow * 128 + (scol + j * 8) * 2) ^ ((srow & 7) << 4);
                *(bf16x8*)((char*)Xs  + byte) = cvt8(fx[2*j], fx[2*j+1]);
                *(bf16x8*)((char*)Ws_ + byte) = cvt8(fw[2*j], fw[2*j+1]);
            }
        }
        __syncthreads();
        #pragma unroll
        for (int kk = 0; kk < 2; kk++) {
            bf16x8 af[4], bfr[4];
            #pragma unroll
            for (int i = 0; i < 4; i++) {
                int row  = wr * 64 + i * 16 + lo;
                af[i]  = lds_read8(Xs,  (row  * 128 + kk * 64 + hi * 16) ^ ((row  & 7) << 4));
                int drow = wc * 64 + i * 16 + lo;
                bfr[i] = lds_read8(Ws_, (drow * 128 + kk * 64 + hi * 16) ^ ((drow & 7) << 4));
            }
            #pragma unroll
            for (int i = 0; i < 4; i++)
                #pragma unroll
                for (int j = 0; j < 4; j++)
                    acc[i][j] = __builtin_amdgcn_mfma_f32_16x16x32_bf16(af[i], bfr[j], acc[i][j], 0, 0, 0);
        }
    }

    float bv4[4];
    #pragma unroll
    for (int j = 0; j < 4; j++) bv4[j] = bias[wc * 64 + j * 16 + lo];

    if (y < 2) {
        bf16_t* outp = (y == 0) ? qo : ko;
        #pragma unroll
        for (int i = 0; i < 4; i++)
            #pragma unroll
            for (int j = 0; j < 4; j++) {
                int d = wc * 64 + j * 16 + lo;
                #pragma unroll
                for (int r = 0; r < 4; r++) {
                    int mrow = m0 + wr * 64 + i * 16 + hi * 4 + r;
                    outp[(size_t)mrow * Dd + d] = (bf16_t)(acc[i][j][r] + bv4[j]);
                }
            }
    } else {
        #pragma unroll
        for (int i = 0; i < 4; i++)
            #pragma unroll
            for (int j = 0; j < 4; j++) {
                int d = wc * 64 + j * 16 + lo;
                #pragma unroll
                for (int r = 0; r < 4; r++) {
                    int mrow = m0 + wr * 64 + i * 16 + hi * 4 + r;
                    vTo[(size_t)d * Mm + mrow] = (bf16_t)(acc[i][j][r] + bv4[j]);
                }
            }
    }
}

// ---------------- causal flash attention ----------------
// grid (Tt/64, Bz), block 256 (4 waves x 16 q-rows each)
__global__ __launch_bounds__(256) void attn_kernel(
    const bf16_t* __restrict__ qi, const bf16_t* __restrict__ ki,
    const bf16_t* __restrict__ vTi, float* __restrict__ out)
{
    const int b  = blockIdx.y;
    const int qt = blockIdx.x;
    const int q0 = qt * 64;
    const int tid  = threadIdx.x;
    const int lane = tid & 63;
    const int w    = tid >> 6;
    const int lo   = lane & 15;
    const int hi   = lane >> 4;

    __shared__ bf16_t Ks[64 * 128];    // [s][d], rows 256B, XOR-swizzled
    __shared__ bf16_t Vs[128 * 64];    // [d][s], rows 128B, XOR-swizzled
    __shared__ bf16_t Ps[4][16 * 64];  // per-wave P [q][s], rows 128B, swizzled

    const float SCALE = 1.4426950408889634f / 32.0f;  // log2(e)/sqrt(C)

    bf16x8 qf[4];
    {
        const bf16_t* qrow = qi + (size_t)(b * Tt + q0 + w * 16 + lo) * Dd;
        #pragma unroll
        for (int kk = 0; kk < 4; kk++)
            qf[kk] = *(const bf16x8*)(qrow + kk * 32 + hi * 8);
    }

    f32x4 zero4 = {0.f, 0.f, 0.f, 0.f};
    f32x4 accO[8];
    #pragma unroll
    for (int i = 0; i < 8; i++) accO[i] = zero4;
    float mrun[4], lrun[4];
    #pragma unroll
    for (int r = 0; r < 4; r++) { mrun[r] = -INFINITY; lrun[r] = 0.f; }

    const int krow = tid >> 2;          // 0..63
    const int kcol = (tid & 3) * 32;
    const int vrow = tid >> 1;          // 0..127
    const int vcol = (tid & 1) * 32;

    for (int t = 0; t <= qt; t++) {
        const int kv0 = t * 64;
        __syncthreads();
        {   // stage K tile [64][128]
            const bf16_t* src = ki + (size_t)(b * Tt + kv0 + krow) * Dd + kcol;
            #pragma unroll
            for (int i = 0; i < 4; i++) {
                bf16x8 v = *(const bf16x8*)(src + i * 8);
                int byte = (krow * 256 + (kcol + i * 8) * 2) ^ ((krow & 7) << 4);
                *(bf16x8*)((char*)Ks + byte) = v;
            }
        }
        {   // stage V^T tile [128][64]
            const bf16_t* src = vTi + (size_t)vrow * Mm + (b * Tt + kv0 + vcol);
            #pragma unroll
            for (int i = 0; i < 4; i++) {
                bf16x8 v = *(const bf16x8*)(src + i * 8);
                int byte = (vrow * 128 + (vcol + i * 8) * 2) ^ ((vrow & 7) << 4);
                *(bf16x8*)((char*)Vs + byte) = v;
            }
        }
        __syncthreads();

        // S = Q K^T : wave's 16 q-rows x 64 s-cols, contract over d=128
        f32x4 accS[4];
        #pragma unroll
        for (int sc = 0; sc < 4; sc++) accS[sc] = zero4;
        #pragma unroll
        for (int kk = 0; kk < 4; kk++)
            #pragma unroll
            for (int sc = 0; sc < 4; sc++) {
                int sr = sc * 16 + lo;
                bf16x8 kf = lds_read8(Ks, (sr * 256 + kk * 64 + hi * 16) ^ ((sr & 7) << 4));
                accS[sc] = __builtin_amdgcn_mfma_f32_16x16x32_bf16(qf[kk], kf, accS[sc], 0, 0, 0);
            }

        // online softmax (log2 domain); causal mask applied pre-max
        float p[4][4];
        #pragma unroll
        for (int sc = 0; sc < 4; sc++) {
            int sg = kv0 + sc * 16 + lo;
            #pragma unroll
            for (int r = 0; r < 4; r++) {
                int qg = q0 + w * 16 + hi * 4 + r;
                float vv = accS[sc][r] * SCALE;
                p[sc][r] = (sg <= qg) ? vv : -INFINITY;
            }
        }
        #pragma unroll
        for (int r = 0; r < 4; r++) {
            float m = fmaxf(fmaxf(p[0][r], p[1][r]), fmaxf(p[2][r], p[3][r]));
            m = fmaxf(m, __shfl_xor(m, 1, 64));
            m = fmaxf(m, __shfl_xor(m, 2, 64));
            m = fmaxf(m, __shfl_xor(m, 4, 64));
            m = fmaxf(m, __shfl_xor(m, 8, 64));
            float mnew = fmaxf(mrun[r], m);
            float muse = (mnew == -INFINITY) ? 0.f : mnew;
            float alpha = exp2f(mrun[r] - muse);
            mrun[r] = mnew;
            float psum = 0.f;
            #pragma unroll
            for (int sc = 0; sc < 4; sc++) {
                float pv = exp2f(p[sc][r] - muse);
                p[sc][r] = pv;
                psum += pv;
            }
            psum += __shfl_xor(psum, 1, 64);
            psum += __shfl_xor(psum, 2, 64);
            psum += __shfl_xor(psum, 4, 64);
            psum += __shfl_xor(psum, 8, 64);
            lrun[r] = alpha * lrun[r] + psum;
            #pragma unroll
            for (int dc = 0; dc < 8; dc++) accO[dc][r] *= alpha;
        }

        // P (C-layout) -> per-wave LDS -> A-fragment layout
        bf16_t* Pw = Ps[w];
        #pragma unroll
        for (int sc = 0; sc < 4; sc++)
            #pragma unroll
            for (int r = 0; r < 4; r++) {
                int qr = hi * 4 + r;
                int byte = (qr * 128 + (sc * 16 + lo) * 2) ^ ((qr & 7) << 4);
                *(bf16_t*)((char*)Pw + byte) = (bf16_t)p[sc][r];
            }

        // O += P @ V  (A = P rows q, B = V^T rows d -> contiguous s runs)
        #pragma unroll
        for (int kk = 0; kk < 2; kk++) {
            bf16x8 pf = lds_read8(Pw, (lo * 128 + kk * 64 + hi * 16) ^ ((lo & 7) << 4));
            #pragma unroll
            for (int dc = 0; dc < 8; dc++) {
                int dr = dc * 16 + lo;
                bf16x8 vf = lds_read8(Vs, (dr * 128 + kk * 64 + hi * 16) ^ ((dr & 7) << 4));
                accO[dc] = __builtin_amdgcn_mfma_f32_16x16x32_bf16(pf, vf, accO[dc], 0, 0, 0);
            }
        }
    }

    #pragma unroll
    for (int r = 0; r < 4; r++) {
        float inv = 1.0f / lrun[r];
        float* orow = out + (size_t)(b * Tt + q0 + w * 16 + hi * 4 + r) * Dd;
        #pragma unroll
        for (int dc = 0; dc < 8; dc++)
            orow[dc * 16 + lo] = accO[dc][r] * inv;
    }
}

extern "C" void kernel_launch(void* const* d_in, const int* in_sizes, int n_in,
                              void* d_out, int out_size, void* d_ws, size_t ws_size,
                              hipStream_t stream)
{
    const float* x  = (const float*)d_in[0];
    const float* Wq = (const float*)d_in[1];
    const float* bq = (const float*)d_in[2];
    const float* Wk = (const float*)d_in[3];
    const float* bk = (const float*)d_in[4];
    const float* Wv = (const float*)d_in[5];
    const float* bv = (const float*)d_in[6];
    float* out = (float*)d_out;

    bf16_t* qb = (bf16_t*)d_ws;                 // [M][D] bf16, 4 MB
    bf16_t* kb = qb + (size_t)Mm * Dd;          // [M][D] bf16, 4 MB
    bf16_t* vT = kb + (size_t)Mm * Dd;          // [D][M] bf16, 4 MB

    qkv_kernel<<<dim3(Mm / 128, 3), 256, 0, stream>>>(x, Wq, bq, Wk, bk, Wv, bv, qb, kb, vT);
    attn_kernel<<<dim3(Tt / 64, Bz), 256, 0, stream>>>(qb, kb, vT, out);
}

// Round 4
// 144.456 us; speedup vs baseline: 1.1644x; 1.1644x over previous
//
#include <hip/hip_runtime.h>
#include <hip/hip_bf16.h>
#include <math.h>

typedef __bf16 bf16_t;
typedef __bf16 bf16x8 __attribute__((ext_vector_type(8)));
typedef float  f32x4  __attribute__((ext_vector_type(4)));

static constexpr int Bz = 8, Tt = 2048, Cc = 1024, Dd = 128;
static constexpr int Mm = Bz * Tt;   // 16384
static constexpr int NT64 = Tt / 64; // 32 q-tiles per batch

__device__ __forceinline__ bf16x8 lds_read8(const bf16_t* base, int byte) {
    return *(const bf16x8*)((const char*)base + byte);
}

__device__ __forceinline__ bf16x8 cvt8(float4 a, float4 b) {
    bf16x8 r;
    r[0] = (bf16_t)a.x; r[1] = (bf16_t)a.y; r[2] = (bf16_t)a.z; r[3] = (bf16_t)a.w;
    r[4] = (bf16_t)b.x; r[5] = (bf16_t)b.y; r[6] = (bf16_t)b.z; r[7] = (bf16_t)b.w;
    return r;
}

// ---------------- QKV projection GEMM ----------------
// grid (Mm/64, 3), block 256 (4 waves as 2x2 of 32x64).
// y==0 -> q [M][D], y==1 -> k [M][D], y==2 -> vT [D][M]
// (re-submit: rounds 2 and 3 both died to container infra failures)
__global__ __launch_bounds__(256, 3) void qkv_kernel(
    const float* __restrict__ x,
    const float* __restrict__ Wq, const float* __restrict__ bq,
    const float* __restrict__ Wk, const float* __restrict__ bk,
    const float* __restrict__ Wv, const float* __restrict__ bv,
    bf16_t* __restrict__ qo, bf16_t* __restrict__ ko, bf16_t* __restrict__ vTo)
{
    const int y = blockIdx.y;
    const float* W    = (y == 0) ? Wq : (y == 1) ? Wk : Wv;
    const float* bias = (y == 0) ? bq : (y == 1) ? bk : bv;

    const int m0   = blockIdx.x * 64;
    const int tid  = threadIdx.x;
    const int lane = tid & 63;
    const int w    = tid >> 6;
    const int wr   = w >> 1;          // wave row (0..1) * 32
    const int wc   = w & 1;           // wave col (0..1) * 64
    const int lo   = lane & 15;
    const int hi   = lane >> 4;

    __shared__ bf16_t Xs[2][64 * 64];    // [m][c] bf16, rows 128B, XOR-swizzled
    __shared__ bf16_t Ws_[2][128 * 64];  // [d][c] bf16, rows 128B, XOR-swizzled

    f32x4 zero4 = {0.f, 0.f, 0.f, 0.f};
    f32x4 acc[2][4];
    #pragma unroll
    for (int i = 0; i < 2; i++)
        #pragma unroll
        for (int j = 0; j < 4; j++) acc[i][j] = zero4;

    const int xrow = tid >> 2;          // 0..63
    const int xcol = (tid & 3) * 16;    // 16 floats each
    const int wrow = tid >> 1;          // 0..127
    const int wcol = (tid & 1) * 32;    // 32 floats each

    float4 fx[4], fw[8];

    auto load_regs = [&](int k0) {
        const float4* sx = (const float4*)(x + (size_t)(m0 + xrow) * Cc + k0 + xcol);
        #pragma unroll
        for (int i = 0; i < 4; i++) fx[i] = sx[i];
        const float4* sw = (const float4*)(W + (size_t)wrow * Cc + k0 + wcol);
        #pragma unroll
        for (int i = 0; i < 8; i++) fw[i] = sw[i];
    };
    auto write_lds = [&](int buf) {
        #pragma unroll
        for (int j = 0; j < 2; j++) {
            int byte = (xrow * 128 + (xcol + j * 8) * 2) ^ ((xrow & 7) << 4);
            *(bf16x8*)((char*)Xs[buf] + byte) = cvt8(fx[2*j], fx[2*j+1]);
        }
        #pragma unroll
        for (int j = 0; j < 4; j++) {
            int byte = (wrow * 128 + (wcol + j * 8) * 2) ^ ((wrow & 7) << 4);
            *(bf16x8*)((char*)Ws_[buf] + byte) = cvt8(fw[2*j], fw[2*j+1]);
        }
    };

    load_regs(0);
    write_lds(0);
    int buf = 0;
    for (int k0 = 0; k0 < Cc; k0 += 64) {
        __syncthreads();
        const bool more = (k0 + 64 < Cc);
        if (more) load_regs(k0 + 64);      // in flight during MFMA below
        #pragma unroll
        for (int kk = 0; kk < 2; kk++) {
            bf16x8 af[2], bfr[4];
            #pragma unroll
            for (int i = 0; i < 2; i++) {
                int row = wr * 32 + i * 16 + lo;
                af[i] = lds_read8(Xs[buf], (row * 128 + kk * 64 + hi * 16) ^ ((row & 7) << 4));
            }
            #pragma unroll
            for (int j = 0; j < 4; j++) {
                int drow = wc * 64 + j * 16 + lo;
                bfr[j] = lds_read8(Ws_[buf], (drow * 128 + kk * 64 + hi * 16) ^ ((drow & 7) << 4));
            }
            #pragma unroll
            for (int i = 0; i < 2; i++)
                #pragma unroll
                for (int j = 0; j < 4; j++)
                    acc[i][j] = __builtin_amdgcn_mfma_f32_16x16x32_bf16(af[i], bfr[j], acc[i][j], 0, 0, 0);
        }
        if (more) write_lds(buf ^ 1);      // other buffer; visible after next barrier
        buf ^= 1;
    }

    float bv4[4];
    #pragma unroll
    for (int j = 0; j < 4; j++) bv4[j] = bias[wc * 64 + j * 16 + lo];

    if (y < 2) {
        bf16_t* outp = (y == 0) ? qo : ko;
        #pragma unroll
        for (int i = 0; i < 2; i++)
            #pragma unroll
            for (int j = 0; j < 4; j++) {
                int d = wc * 64 + j * 16 + lo;
                #pragma unroll
                for (int r = 0; r < 4; r++) {
                    int mrow = m0 + wr * 32 + i * 16 + hi * 4 + r;
                    outp[(size_t)mrow * Dd + d] = (bf16_t)(acc[i][j][r] + bv4[j]);
                }
            }
    } else {
        #pragma unroll
        for (int i = 0; i < 2; i++)
            #pragma unroll
            for (int j = 0; j < 4; j++) {
                int d = wc * 64 + j * 16 + lo;
                #pragma unroll
                for (int r = 0; r < 4; r++) {
                    int mrow = m0 + wr * 32 + i * 16 + hi * 4 + r;
                    vTo[(size_t)d * Mm + mrow] = (bf16_t)(acc[i][j][r] + bv4[j]);
                }
            }
    }
}

// ---------------- causal flash attention (KV-split partials) ----------------
// 1-D grid of 32*nsplit*8 blocks, 256 threads (4 waves x 16 q-rows).
// Block g: qt = 31 - g/(nsplit*8) (LPT order), s = (g%(nsplit*8))/8, b = g%8.
// Writes unnormalized O partial + per-row (m, l) in log2 domain.
__global__ __launch_bounds__(256, 3) void attn_kernel(
    const bf16_t* __restrict__ qi, const bf16_t* __restrict__ ki,
    const bf16_t* __restrict__ vTi,
    float* __restrict__ Opart, float* __restrict__ Mpart, float* __restrict__ Lpart,
    int nsplit)
{
    const int g   = blockIdx.x;
    const int per = nsplit * 8;
    const int qt  = (NT64 - 1) - g / per;
    const int rem = g % per;
    const int s   = rem >> 3;
    const int b   = rem & 7;
    const int nt  = qt + 1;
    const int t_lo = (s * nt) / nsplit;
    const int t_hi = ((s + 1) * nt) / nsplit;

    const int q0   = qt * 64;
    const int tid  = threadIdx.x;
    const int lane = tid & 63;
    const int w    = tid >> 6;
    const int lo   = lane & 15;
    const int hi   = lane >> 4;

    float* Ob = Opart + ((size_t)s * Mm + (size_t)b * Tt + q0) * Dd;
    float* Mb = Mpart + (size_t)s * Mm + (size_t)b * Tt + q0;
    float* Lb = Lpart + (size_t)s * Mm + (size_t)b * Tt + q0;

    if (t_lo >= t_hi) {  // empty split range: zero partial
        #pragma unroll
        for (int r = 0; r < 4; r++) {
            int row = w * 16 + hi * 4 + r;
            #pragma unroll
            for (int dc = 0; dc < 8; dc++) Ob[(size_t)row * Dd + dc * 16 + lo] = 0.f;
            if (lo == 0) { Mb[row] = -INFINITY; Lb[row] = 0.f; }
        }
        return;
    }

    __shared__ bf16_t Ks[64 * 128];    // [s][d], rows 256B, XOR-swizzled
    __shared__ bf16_t Vs[128 * 64];    // [d][s], rows 128B, XOR-swizzled
    __shared__ bf16_t Ps[4][16 * 64];  // per-wave P [q][s], rows 128B, swizzled

    const float SCALE = 1.4426950408889634f / 32.0f;  // log2(e)/sqrt(C)

    bf16x8 qf[4];
    {
        const bf16_t* qrow = qi + (size_t)(b * Tt + q0 + w * 16 + lo) * Dd;
        #pragma unroll
        for (int kk = 0; kk < 4; kk++)
            qf[kk] = *(const bf16x8*)(qrow + kk * 32 + hi * 8);
    }

    f32x4 zero4 = {0.f, 0.f, 0.f, 0.f};
    f32x4 accO[8];
    #pragma unroll
    for (int i = 0; i < 8; i++) accO[i] = zero4;
    float mrun[4], lrun[4];
    #pragma unroll
    for (int r = 0; r < 4; r++) { mrun[r] = -INFINITY; lrun[r] = 0.f; }

    const int krow = tid >> 2;          // 0..63
    const int kcol = (tid & 3) * 32;
    const int vrow = tid >> 1;          // 0..127
    const int vcol = (tid & 1) * 32;

    bf16x8 kr[4], vr[4];
    auto load_kv = [&](int t) {
        const int kv0 = t * 64;
        const bf16_t* ksrc = ki + (size_t)(b * Tt + kv0 + krow) * Dd + kcol;
        #pragma unroll
        for (int i = 0; i < 4; i++) kr[i] = *(const bf16x8*)(ksrc + i * 8);
        const bf16_t* vsrc = vTi + (size_t)vrow * Mm + (b * Tt + kv0 + vcol);
        #pragma unroll
        for (int i = 0; i < 4; i++) vr[i] = *(const bf16x8*)(vsrc + i * 8);
    };
    auto write_kv = [&]() {
        #pragma unroll
        for (int i = 0; i < 4; i++) {
            int byte = (krow * 256 + (kcol + i * 8) * 2) ^ ((krow & 7) << 4);
            *(bf16x8*)((char*)Ks + byte) = kr[i];
        }
        #pragma unroll
        for (int i = 0; i < 4; i++) {
            int byte = (vrow * 128 + (vcol + i * 8) * 2) ^ ((vrow & 7) << 4);
            *(bf16x8*)((char*)Vs + byte) = vr[i];
        }
    };

    load_kv(t_lo);
    write_kv();
    __syncthreads();

    for (int t = t_lo; t < t_hi; t++) {
        const int kv0 = t * 64;
        const bool more = (t + 1 < t_hi);
        if (more) load_kv(t + 1);          // in flight during compute

        // S = Q K^T : wave's 16 q-rows x 64 s-cols, contract over d=128
        f32x4 accS[4];
        #pragma unroll
        for (int sc = 0; sc < 4; sc++) accS[sc] = zero4;
        #pragma unroll
        for (int kk = 0; kk < 4; kk++)
            #pragma unroll
            for (int sc = 0; sc < 4; sc++) {
                int sr = sc * 16 + lo;
                bf16x8 kf = lds_read8(Ks, (sr * 256 + kk * 64 + hi * 16) ^ ((sr & 7) << 4));
                accS[sc] = __builtin_amdgcn_mfma_f32_16x16x32_bf16(qf[kk], kf, accS[sc], 0, 0, 0);
            }

        // online softmax (log2 domain); mask only on the diagonal tile
        const bool diag = (t == qt);
        float p[4][4];
        #pragma unroll
        for (int sc = 0; sc < 4; sc++) {
            int sg = kv0 + sc * 16 + lo;
            #pragma unroll
            for (int r = 0; r < 4; r++) {
                float vv = accS[sc][r] * SCALE;
                int qg = q0 + w * 16 + hi * 4 + r;
                p[sc][r] = (diag && sg > qg) ? -INFINITY : vv;
            }
        }
        #pragma unroll
        for (int r = 0; r < 4; r++) {
            float m = fmaxf(fmaxf(p[0][r], p[1][r]), fmaxf(p[2][r], p[3][r]));
            m = fmaxf(m, __shfl_xor(m, 1, 64));
            m = fmaxf(m, __shfl_xor(m, 2, 64));
            m = fmaxf(m, __shfl_xor(m, 4, 64));
            m = fmaxf(m, __shfl_xor(m, 8, 64));
            float mnew = fmaxf(mrun[r], m);
            float muse = (mnew == -INFINITY) ? 0.f : mnew;
            float alpha = exp2f(mrun[r] - muse);
            mrun[r] = mnew;
            float psum = 0.f;
            #pragma unroll
            for (int sc = 0; sc < 4; sc++) {
                float pv = exp2f(p[sc][r] - muse);
                p[sc][r] = pv;
                psum += pv;
            }
            psum += __shfl_xor(psum, 1, 64);
            psum += __shfl_xor(psum, 2, 64);
            psum += __shfl_xor(psum, 4, 64);
            psum += __shfl_xor(psum, 8, 64);
            lrun[r] = alpha * lrun[r] + psum;
            #pragma unroll
            for (int dc = 0; dc < 8; dc++) accO[dc][r] *= alpha;
        }

        // P (C-layout) -> per-wave LDS -> A-fragment layout
        bf16_t* Pw = Ps[w];
        #pragma unroll
        for (int sc = 0; sc < 4; sc++)
            #pragma unroll
            for (int r = 0; r < 4; r++) {
                int qr = hi * 4 + r;
                int byte = (qr * 128 + (sc * 16 + lo) * 2) ^ ((qr & 7) << 4);
                *(bf16_t*)((char*)Pw + byte) = (bf16_t)p[sc][r];
            }

        // O += P @ V
        #pragma unroll
        for (int kk = 0; kk < 2; kk++) {
            bf16x8 pf = lds_read8(Pw, (lo * 128 + kk * 64 + hi * 16) ^ ((lo & 7) << 4));
            #pragma unroll
            for (int dc = 0; dc < 8; dc++) {
                int dr = dc * 16 + lo;
                bf16x8 vf = lds_read8(Vs, (dr * 128 + kk * 64 + hi * 16) ^ ((dr & 7) << 4));
                accO[dc] = __builtin_amdgcn_mfma_f32_16x16x32_bf16(pf, vf, accO[dc], 0, 0, 0);
            }
        }

        __syncthreads();                    // all waves done reading Ks/Vs
        if (more) write_kv();               // overwrite with prefetched tile
        __syncthreads();
    }

    // unnormalized partial + (m, l)
    #pragma unroll
    for (int r = 0; r < 4; r++) {
        int row = w * 16 + hi * 4 + r;
        float* orow = Ob + (size_t)row * Dd;
        #pragma unroll
        for (int dc = 0; dc < 8; dc++)
            orow[dc * 16 + lo] = accO[dc][r];
        if (lo == 0) { Mb[row] = mrun[r]; Lb[row] = lrun[r]; }
    }
}

// ---------------- split combine + normalize ----------------
// one float4 of out per thread
__global__ __launch_bounds__(256) void combine_kernel(
    const float* __restrict__ Opart, const float* __restrict__ Mpart,
    const float* __restrict__ Lpart, float* __restrict__ out, int nsplit)
{
    int t   = blockIdx.x * 256 + threadIdx.x;
    int row = t >> 5;
    int dq  = (t & 31) << 2;
    float M = -INFINITY;
    for (int s = 0; s < nsplit; s++)
        M = fmaxf(M, Mpart[(size_t)s * Mm + row]);
    float L = 0.f;
    float o0 = 0.f, o1 = 0.f, o2 = 0.f, o3 = 0.f;
    for (int s = 0; s < nsplit; s++) {
        float ms = Mpart[(size_t)s * Mm + row];
        float ws = (ms == -INFINITY) ? 0.f : exp2f(ms - M);
        L += ws * Lpart[(size_t)s * Mm + row];
        float4 p = *(const float4*)(Opart + ((size_t)s * Mm + row) * Dd + dq);
        o0 += ws * p.x; o1 += ws * p.y; o2 += ws * p.z; o3 += ws * p.w;
    }
    float inv = 1.0f / L;
    float4 r; r.x = o0 * inv; r.y = o1 * inv; r.z = o2 * inv; r.w = o3 * inv;
    *(float4*)(out + (size_t)row * Dd + dq) = r;
}

extern "C" void kernel_launch(void* const* d_in, const int* in_sizes, int n_in,
                              void* d_out, int out_size, void* d_ws, size_t ws_size,
                              hipStream_t stream)
{
    const float* x  = (const float*)d_in[0];
    const float* Wq = (const float*)d_in[1];
    const float* bq = (const float*)d_in[2];
    const float* Wk = (const float*)d_in[3];
    const float* bk = (const float*)d_in[4];
    const float* Wv = (const float*)d_in[5];
    const float* bv = (const float*)d_in[6];
    float* out = (float*)d_out;

    bf16_t* qb = (bf16_t*)d_ws;                 // [M][D] bf16
    bf16_t* kb = qb + (size_t)Mm * Dd;          // [M][D] bf16
    bf16_t* vT = kb + (size_t)Mm * Dd;          // [D][M] bf16
    char* p = (char*)(vT + (size_t)Mm * Dd);

    auto need = [&](int ns) {
        return (size_t)3 * Mm * Dd * 2 + (size_t)ns * Mm * Dd * 4 + (size_t)ns * Mm * 8;
    };
    int nsplit = 4;
    while (nsplit > 1 && need(nsplit) > ws_size) nsplit >>= 1;

    float* Opart = (float*)p;                                  // [ns][M][D] f32
    float* Mpart = (float*)(p + (size_t)nsplit * Mm * Dd * 4); // [ns][M]
    float* Lpart = Mpart + (size_t)nsplit * Mm;                // [ns][M]

    qkv_kernel<<<dim3(Mm / 64, 3), 256, 0, stream>>>(x, Wq, bq, Wk, bk, Wv, bv, qb, kb, vT);
    attn_kernel<<<dim3(NT64 * nsplit * Bz), 256, 0, stream>>>(qb, kb, vT, Opart, Mpart, Lpart, nsplit);
    combine_kernel<<<dim3(Mm * 32 / 256), 256, 0, stream>>>(Opart, Mpart, Lpart, out, nsplit);
}